// Round 2
// baseline (264.810 us; speedup 1.0000x reference)
//
#include <hip/hip_runtime.h>
#include <hip/hip_bf16.h>

#define BT_TOTAL 1024

typedef __bf16 bf16x8 __attribute__((ext_vector_type(8)));
typedef float  f32x4  __attribute__((ext_vector_type(4)));
typedef int    i32x4  __attribute__((ext_vector_type(4)));
typedef short  s16x4  __attribute__((ext_vector_type(4)));

__device__ inline unsigned short f2bf(float f) {
    unsigned int u = __builtin_bit_cast(unsigned int, f);
    u = (u + 0x7FFFu + ((u >> 16) & 1u)) >> 16;
    return (unsigned short)u;
}

__device__ inline bf16x8 ldsb8(const unsigned short* p) {
    i32x4 t = *(const i32x4*)p;
    return __builtin_bit_cast(bf16x8, t);
}

// -------- fused weight transposes: src [K][N] f32 -> dst [N][K] bf16
__global__ void transpose_all(const float* __restrict__ W1,
                              const float* __restrict__ W2,
                              const float* __restrict__ W3,
                              unsigned short* __restrict__ wt1,
                              unsigned short* __restrict__ wt2,
                              unsigned short* __restrict__ wt3) {
    __shared__ float tile[32][33];
    int bi = blockIdx.x;
    const float* src; unsigned short* dst; int K, N, tiles_x, base;
    if (bi < 64)       { src = W1; dst = wt1; K = 128; N = 512; tiles_x = 16; base = bi; }
    else if (bi < 320) { src = W2; dst = wt2; K = 512; N = 512; tiles_x = 16; base = bi - 64; }
    else               { src = W3; dst = wt3; K = 512; N = 256; tiles_x = 8;  base = bi - 320; }
    int tx = base % tiles_x, ty = base / tiles_x;
    int k0 = ty * 32, n0 = tx * 32;
    int t = threadIdx.x;
    int c = t & 31, r0 = t >> 5;
#pragma unroll
    for (int i = 0; i < 4; ++i) {
        int r = r0 + i * 8;
        tile[r][c] = src[(size_t)(k0 + r) * N + n0 + c];
    }
    __syncthreads();
#pragma unroll
    for (int i = 0; i < 4; ++i) {
        int rr = r0 + i * 8;
        dst[(size_t)(n0 + rr) * K + k0 + c] = f2bf(tile[c][rr]);
    }
}

// ---------------- LDS layout (bytes) ----------------
// MLP phase:
//   H1 @ 0      : [64][528] ushort  = 67584
//   H2 @ 67584  : [64][528] ushort  = 67584   (total 135168)
// Attention overlay (after layer-3 K-loop barrier; H1/H2 dead):
//   EMB_RM @ 0      : [64][264]  us  33792   (emb row-major,  stride 33 x16B odd)
//   EMB_CM @ 33792  : [256][72]  us  36864   (emb col-major)
//   Q_RM   @ 70656  : [16][264]  us   8448
//   T_RM   @ 79104  : [16][264]  us   8448
//   T_CM   @ 87552  : [256][40]  us  20480   (q padded to 40, zeros at 16..39)
//   W1A    @ 108032 : [16][72]   us   2304   (softmax1 weights bf16)
//   W2A    @ 110336 : [64][40]   us   5120   (softmax2 weights bf16, zero pad 16..39)
//   S1F    @ 115456 : [16][68]   f32  4352
//   S2F    @ 119808 : [64][20]   f32  5120
//   MK     @ 124928 : [64]       i32   256
#define LDS_BYTES 135168

__global__ __launch_bounds__(1024, 4) void fused_mlp_attn(
    const float* __restrict__ obs, const int* __restrict__ amask,
    const unsigned short* __restrict__ WT1, const float* __restrict__ b1,
    const unsigned short* __restrict__ WT2, const float* __restrict__ b2,
    const unsigned short* __restrict__ WT3, const float* __restrict__ b3,
    const float* __restrict__ tq,
    float* __restrict__ outT, float* __restrict__ outC)
{
    extern __shared__ __align__(16) char smem[];
    unsigned short* H1     = (unsigned short*)smem;
    unsigned short* H2     = (unsigned short*)(smem + 67584);
    unsigned short* EMB_RM = (unsigned short*)smem;
    unsigned short* EMB_CM = (unsigned short*)(smem + 33792);
    unsigned short* Q_RM   = (unsigned short*)(smem + 70656);
    unsigned short* T_RM   = (unsigned short*)(smem + 79104);
    unsigned short* T_CM   = (unsigned short*)(smem + 87552);
    unsigned short* W1A    = (unsigned short*)(smem + 108032);
    unsigned short* W2A    = (unsigned short*)(smem + 110336);
    float*          S1F    = (float*)(smem + 115456);
    float*          S2F    = (float*)(smem + 119808);
    int*            MK     = (int*)  (smem + 124928);

    const int bt   = blockIdx.x;
    const int tid  = threadIdx.x;
    const int lane = tid & 63;
    const int wave = tid >> 6;      // 0..15
    const int l16  = lane & 15;
    const int l4   = lane >> 4;
    const int wm   = wave >> 3;     // 0..1
    const int wn   = wave & 7;      // 0..7

    const float* obsG = obs + (size_t)bt * (64 * 128);

    // ================= Layer 1: h1 = relu(obs @ W1 + b1) =================
    {
        f32x4 acc[2][4] = {};
        for (int kk = 0; kk < 4; ++kk) {
            const int koff = kk * 32 + l4 * 8;
            bf16x8 afr[2];
#pragma unroll
            for (int mt = 0; mt < 2; ++mt) {
                int row = wm * 32 + mt * 16 + l16;
                const float* p = obsG + row * 128 + koff;
                f32x4 v0 = *(const f32x4*)(p);
                f32x4 v1 = *(const f32x4*)(p + 4);
                bf16x8 a;
                a[0]=(__bf16)v0.x; a[1]=(__bf16)v0.y; a[2]=(__bf16)v0.z; a[3]=(__bf16)v0.w;
                a[4]=(__bf16)v1.x; a[5]=(__bf16)v1.y; a[6]=(__bf16)v1.z; a[7]=(__bf16)v1.w;
                afr[mt] = a;
            }
#pragma unroll
            for (int nt = 0; nt < 4; ++nt) {
                int col = wn * 64 + nt * 16 + l16;
                bf16x8 bfr = ldsb8(WT1 + (size_t)col * 128 + koff);
#pragma unroll
                for (int mt = 0; mt < 2; ++mt)
                    acc[mt][nt] = __builtin_amdgcn_mfma_f32_16x16x32_bf16(afr[mt], bfr, acc[mt][nt], 0, 0, 0);
            }
        }
#pragma unroll
        for (int nt = 0; nt < 4; ++nt) {
            int col = wn * 64 + nt * 16 + l16;
            float bias = b1[col];
#pragma unroll
            for (int mt = 0; mt < 2; ++mt)
#pragma unroll
                for (int i = 0; i < 4; ++i) {
                    int row = wm * 32 + mt * 16 + l4 * 4 + i;
                    float v = acc[mt][nt][i] + bias;
                    H1[row * 528 + col] = f2bf(fmaxf(v, 0.f));
                }
        }
    }
    __syncthreads();

    // ================= Layer 2: h2 = relu(h1 @ W2 + b2) =================
    {
        f32x4 acc[2][4] = {};
        for (int kk = 0; kk < 16; ++kk) {
            const int koff = kk * 32 + l4 * 8;
            bf16x8 afr[2];
#pragma unroll
            for (int mt = 0; mt < 2; ++mt)
                afr[mt] = ldsb8(H1 + (wm * 32 + mt * 16 + l16) * 528 + koff);
#pragma unroll
            for (int nt = 0; nt < 4; ++nt) {
                int col = wn * 64 + nt * 16 + l16;
                bf16x8 bfr = ldsb8(WT2 + (size_t)col * 512 + koff);
#pragma unroll
                for (int mt = 0; mt < 2; ++mt)
                    acc[mt][nt] = __builtin_amdgcn_mfma_f32_16x16x32_bf16(afr[mt], bfr, acc[mt][nt], 0, 0, 0);
            }
        }
#pragma unroll
        for (int nt = 0; nt < 4; ++nt) {
            int col = wn * 64 + nt * 16 + l16;
            float bias = b2[col];
#pragma unroll
            for (int mt = 0; mt < 2; ++mt)
#pragma unroll
                for (int i = 0; i < 4; ++i) {
                    int row = wm * 32 + mt * 16 + l4 * 4 + i;
                    float v = acc[mt][nt][i] + bias;
                    H2[row * 528 + col] = f2bf(fmaxf(v, 0.f));
                }
        }
    }
    __syncthreads();

    // ================= Layer 3: emb = h2 @ W3 + b3 (held in regs) =================
    f32x4 acc3[2][2] = {};
    {
        for (int kk = 0; kk < 16; ++kk) {
            const int koff = kk * 32 + l4 * 8;
            bf16x8 afr[2];
#pragma unroll
            for (int mt = 0; mt < 2; ++mt)
                afr[mt] = ldsb8(H2 + (wm * 32 + mt * 16 + l16) * 528 + koff);
#pragma unroll
            for (int nt = 0; nt < 2; ++nt) {
                int col = wn * 32 + nt * 16 + l16;
                bf16x8 bfr = ldsb8(WT3 + (size_t)col * 512 + koff);
#pragma unroll
                for (int mt = 0; mt < 2; ++mt)
                    acc3[mt][nt] = __builtin_amdgcn_mfma_f32_16x16x32_bf16(afr[mt], bfr, acc3[mt][nt], 0, 0, 0);
            }
        }
    }
    __syncthreads();   // H1/H2 now dead; overlay becomes live

    // ---- layer-3 epilogue: write emb (row-major + col-major bf16) ----
    {
#pragma unroll
        for (int nt = 0; nt < 2; ++nt) {
            int col = wn * 32 + nt * 16 + l16;
            float bias = b3[col];
#pragma unroll
            for (int mt = 0; mt < 2; ++mt)
#pragma unroll
                for (int i = 0; i < 4; ++i) {
                    int row = wm * 32 + mt * 16 + l4 * 4 + i;
                    float v = acc3[mt][nt][i] + bias;
                    unsigned short u = f2bf(v);
                    EMB_RM[row * 264 + col] = u;
                    EMB_CM[col * 72 + row]  = u;
                }
        }
        // stage token queries as bf16 row-major [16][264]
        int q = tid >> 6, d0 = (tid & 63) * 4;
        f32x4 v = *(const f32x4*)(tq + q * 256 + d0);
        s16x4 s;
        s[0] = (short)f2bf(v.x); s[1] = (short)f2bf(v.y);
        s[2] = (short)f2bf(v.z); s[3] = (short)f2bf(v.w);
        *(s16x4*)(Q_RM + q * 264 + d0) = s;
        if (tid < 64) MK[tid] = amask[(size_t)bt * 64 + tid];
    }
    __syncthreads();

    // ---- S1 = Q . emb^T / 16  -> [16 q][64 agents]  (waves 0..3) ----
    if (wave < 4) {
        f32x4 acc = {};
        for (int kk = 0; kk < 8; ++kk) {
            int koff = kk * 32 + l4 * 8;
            bf16x8 a = ldsb8(Q_RM + l16 * 264 + koff);
            bf16x8 b = ldsb8(EMB_RM + (wave * 16 + l16) * 264 + koff);
            acc = __builtin_amdgcn_mfma_f32_16x16x32_bf16(a, b, acc, 0, 0, 0);
        }
#pragma unroll
        for (int i = 0; i < 4; ++i) {
            int q = l4 * 4 + i, m = wave * 16 + l16;
            S1F[q * 68 + m] = acc[i] * 0.0625f;
        }
    }
    __syncthreads();

    // ---- masked softmax over agents; weights -> W1A bf16 (wave = q row) ----
    {
        int q = wave, m = lane;
        int msk = MK[m];
        float s = S1F[q * 68 + m];
        float sv = msk ? s : -1e30f;
        float mx = sv;
#pragma unroll
        for (int off = 32; off >= 1; off >>= 1) mx = fmaxf(mx, __shfl_xor(mx, off));
        float ev = msk ? __expf(sv - mx) : 0.f;
        float se = ev;
#pragma unroll
        for (int off = 32; off >= 1; off >>= 1) se += __shfl_xor(se, off);
        float w = ev * (1.0f / fmaxf(se, 1e-8f));
        W1A[q * 72 + m] = f2bf(w);
    }
    __syncthreads();

    // ---- T = W1A @ emb -> [16 q][256 d]  (wave = d-tile) ----
    {
        f32x4 acc = {};
#pragma unroll
        for (int kk = 0; kk < 2; ++kk) {
            int koff = kk * 32 + l4 * 8;
            bf16x8 a = ldsb8(W1A + l16 * 72 + koff);
            bf16x8 b = ldsb8(EMB_CM + (wave * 16 + l16) * 72 + koff);
            acc = __builtin_amdgcn_mfma_f32_16x16x32_bf16(a, b, acc, 0, 0, 0);
        }
        int d = wave * 16 + l16;
        float* oT = outT + (size_t)bt * (16 * 256);
#pragma unroll
        for (int i = 0; i < 4; ++i) {
            int q = l4 * 4 + i;
            float v = acc[i];
            unsigned short u = f2bf(v);
            T_RM[q * 264 + d] = u;
            T_CM[d * 40 + q] = u;
            T_CM[d * 40 + q + 16] = 0;
            if (l4 < 2) T_CM[d * 40 + q + 32] = 0;
            oT[q * 256 + d] = v;
        }
    }
    __syncthreads();

    // ---- S2 = emb . T^T / 16 -> [64 agents][16 q]  (waves 0..3 = m-tiles) ----
    if (wave < 4) {
        f32x4 acc = {};
        for (int kk = 0; kk < 8; ++kk) {
            int koff = kk * 32 + l4 * 8;
            bf16x8 a = ldsb8(EMB_RM + (wave * 16 + l16) * 264 + koff);
            bf16x8 b = ldsb8(T_RM + l16 * 264 + koff);
            acc = __builtin_amdgcn_mfma_f32_16x16x32_bf16(a, b, acc, 0, 0, 0);
        }
#pragma unroll
        for (int i = 0; i < 4; ++i) {
            int ag = wave * 16 + l4 * 4 + i;
            S2F[ag * 20 + l16] = acc[i] * 0.0625f;
        }
    }
    __syncthreads();

    // ---- softmax over q (16); weights -> W2A bf16, zero-padded K=40 ----
    {
        int j = tid >> 4, i = tid & 15;
        float s = S2F[j * 20 + i];
        float mx = s;
#pragma unroll
        for (int off = 8; off >= 1; off >>= 1) mx = fmaxf(mx, __shfl_xor(mx, off, 16));
        float ev = __expf(s - mx);
        float se = ev;
#pragma unroll
        for (int off = 8; off >= 1; off >>= 1) se += __shfl_xor(se, off, 16);
        float w = ev / se;
        W2A[j * 40 + i] = f2bf(w);
        W2A[j * 40 + i + 16] = 0;
        if (i < 8) W2A[j * 40 + i + 32] = 0;
    }
    __syncthreads();

    // ---- ctx = (W2A @ T) * mask -> [64 agents][256 d] ----
    {
        int mt = wave >> 2, ng = wave & 3;
        bf16x8 a = ldsb8(W2A + (mt * 16 + l16) * 40 + l4 * 8);
        float* oC = outC + (size_t)bt * (64 * 256);
#pragma unroll
        for (int c = 0; c < 4; ++c) {
            int d = (ng * 4 + c) * 16 + l16;
            bf16x8 b = ldsb8(T_CM + d * 40 + l4 * 8);
            f32x4 acc = {};
            acc = __builtin_amdgcn_mfma_f32_16x16x32_bf16(a, b, acc, 0, 0, 0);
#pragma unroll
            for (int i = 0; i < 4; ++i) {
                int ag = mt * 16 + l4 * 4 + i;
                float m = (float)MK[ag];
                oC[ag * 256 + d] = acc[i] * m;
            }
        }
    }
}

extern "C" void kernel_launch(void* const* d_in, const int* in_sizes, int n_in,
                              void* d_out, int out_size, void* d_ws, size_t ws_size,
                              hipStream_t stream) {
    (void)in_sizes; (void)n_in; (void)out_size; (void)ws_size;
    const float* obs   = (const float*)d_in[0];
    const int*   amask = (const int*)d_in[1];
    const float* W1    = (const float*)d_in[2];
    const float* b1    = (const float*)d_in[3];
    const float* W2    = (const float*)d_in[4];
    const float* b2    = (const float*)d_in[5];
    const float* W3    = (const float*)d_in[6];
    const float* b3    = (const float*)d_in[7];
    const float* tq    = (const float*)d_in[8];

    unsigned short* wt1 = (unsigned short*)d_ws;          // [512][128]
    unsigned short* wt2 = wt1 + 512 * 128;                // [512][512]
    unsigned short* wt3 = wt2 + 512 * 512;                // [256][512]

    float* outT = (float*)d_out;
    float* outC = outT + (size_t)BT_TOTAL * 16 * 256;

    transpose_all<<<448, 256, 0, stream>>>(W1, W2, W3, wt1, wt2, wt3);
    fused_mlp_attn<<<BT_TOTAL, 1024, LDS_BYTES, stream>>>(
        obs, amask, wt1, b1, wt2, b2, wt3, b3, tq, outT, outC);
}

// Round 3
// 263.224 us; speedup vs baseline: 1.0060x; 1.0060x over previous
//
#include <hip/hip_runtime.h>
#include <hip/hip_bf16.h>

#define BT_TOTAL 1024

typedef __bf16 bf16x8 __attribute__((ext_vector_type(8)));
typedef float  f32x4  __attribute__((ext_vector_type(4)));
typedef int    i32x4  __attribute__((ext_vector_type(4)));
typedef short  s16x4  __attribute__((ext_vector_type(4)));

__device__ inline unsigned short f2bf(float f) {
    unsigned int u = __builtin_bit_cast(unsigned int, f);
    u = (u + 0x7FFFu + ((u >> 16) & 1u)) >> 16;
    return (unsigned short)u;
}

__device__ inline bf16x8 ldsb8(const unsigned short* p) {
    i32x4 t = *(const i32x4*)p;
    return __builtin_bit_cast(bf16x8, t);
}

// -------- weight transposes (f32 [K][N] -> bf16 [N][K]) + tq bf16 copy
__global__ void transpose_all(const float* __restrict__ W1,
                              const float* __restrict__ W2,
                              const float* __restrict__ W3,
                              const float* __restrict__ tq,
                              unsigned short* __restrict__ wt1,
                              unsigned short* __restrict__ wt2,
                              unsigned short* __restrict__ wt3,
                              unsigned short* __restrict__ tqbf) {
    int bi = blockIdx.x;
    if (bi == 448) {
#pragma unroll
        for (int i = 0; i < 16; ++i) {
            int idx = threadIdx.x + i * 256;
            tqbf[idx] = f2bf(tq[idx]);
        }
        return;
    }
    __shared__ float tile[32][33];
    const float* src; unsigned short* dst; int K, N, tiles_x, base;
    if (bi < 64)       { src = W1; dst = wt1; K = 128; N = 512; tiles_x = 16; base = bi; }
    else if (bi < 320) { src = W2; dst = wt2; K = 512; N = 512; tiles_x = 16; base = bi - 64; }
    else               { src = W3; dst = wt3; K = 512; N = 256; tiles_x = 8;  base = bi - 320; }
    int tx = base % tiles_x, ty = base / tiles_x;
    int k0 = ty * 32, n0 = tx * 32;
    int t = threadIdx.x;
    int c = t & 31, r0 = t >> 5;
#pragma unroll
    for (int i = 0; i < 4; ++i) {
        int r = r0 + i * 8;
        tile[r][c] = src[(size_t)(k0 + r) * N + n0 + c];
    }
    __syncthreads();
#pragma unroll
    for (int i = 0; i < 4; ++i) {
        int rr = r0 + i * 8;
        dst[(size_t)(n0 + rr) * K + k0 + c] = f2bf(tile[c][rr]);
    }
}

// ======================= K1: fused MLP =======================
// LDS: OBS [64][136] us @0 (17408) ; H [64][536] us @17408 (68608) = 86016
#define K1_LDS 86016

__global__ __launch_bounds__(1024, 4) void mlp_kernel(
    const float* __restrict__ obs,
    const unsigned short* __restrict__ WT1, const float* __restrict__ b1,
    const unsigned short* __restrict__ WT2, const float* __restrict__ b2,
    const unsigned short* __restrict__ WT3, const float* __restrict__ b3,
    unsigned short* __restrict__ embOut)   // per bt: RM [64][256] then CM [256][64]
{
    extern __shared__ __align__(16) char smem[];
    unsigned short* OBS = (unsigned short*)smem;            // [64][136]
    unsigned short* H   = (unsigned short*)(smem + 17408);  // [64][536]

    const int bt = blockIdx.x, tid = threadIdx.x;
    const int lane = tid & 63, wave = tid >> 6;
    const int l16 = lane & 15, l4 = lane >> 4;
    const int wm = wave >> 3, wn = wave & 7;

    // ---- stage obs -> bf16 LDS (coalesced) ----
    {
        const f32x4* src = (const f32x4*)(obs + (size_t)bt * 8192);
#pragma unroll
        for (int i = 0; i < 2; ++i) {
            int idx = tid + i * 1024;           // 2048 f32x4
            f32x4 v = src[idx];
            int row = idx >> 5, c4 = idx & 31;
            s16x4 s;
            s[0] = (short)f2bf(v.x); s[1] = (short)f2bf(v.y);
            s[2] = (short)f2bf(v.z); s[3] = (short)f2bf(v.w);
            *(s16x4*)(OBS + row * 136 + c4 * 4) = s;
        }
    }
    __syncthreads();

    // ---- L1: H1 = relu(obs @ W1 + b1), K=128 ----
    {
        f32x4 acc[2][4] = {};
        bf16x8 aq[2][2], bq[3][4];
#pragma unroll
        for (int nt = 0; nt < 4; ++nt) bq[0][nt] = ldsb8(WT1 + (size_t)(wn*64 + nt*16 + l16) * 128 + l4*8);
#pragma unroll
        for (int nt = 0; nt < 4; ++nt) bq[1][nt] = ldsb8(WT1 + (size_t)(wn*64 + nt*16 + l16) * 128 + 32 + l4*8);
#pragma unroll
        for (int mt = 0; mt < 2; ++mt) aq[0][mt] = ldsb8(OBS + (wm*32 + mt*16 + l16) * 136 + l4*8);
#pragma unroll
        for (int kk = 0; kk < 4; ++kk) {
            if (kk + 2 < 4) {
#pragma unroll
                for (int nt = 0; nt < 4; ++nt)
                    bq[(kk+2)%3][nt] = ldsb8(WT1 + (size_t)(wn*64 + nt*16 + l16) * 128 + (kk+2)*32 + l4*8);
            }
            if (kk + 1 < 4) {
#pragma unroll
                for (int mt = 0; mt < 2; ++mt)
                    aq[(kk+1)&1][mt] = ldsb8(OBS + (wm*32 + mt*16 + l16) * 136 + (kk+1)*32 + l4*8);
            }
#pragma unroll
            for (int nt = 0; nt < 4; ++nt)
#pragma unroll
                for (int mt = 0; mt < 2; ++mt)
                    acc[mt][nt] = __builtin_amdgcn_mfma_f32_16x16x32_bf16(aq[kk&1][mt], bq[kk%3][nt], acc[mt][nt], 0, 0, 0);
        }
#pragma unroll
        for (int nt = 0; nt < 4; ++nt) {
            int col = wn*64 + nt*16 + l16;
            float bias = b1[col];
#pragma unroll
            for (int mt = 0; mt < 2; ++mt)
#pragma unroll
                for (int i = 0; i < 4; ++i) {
                    int row = wm*32 + mt*16 + l4*4 + i;
                    H[row * 536 + col] = f2bf(fmaxf(acc[mt][nt][i] + bias, 0.f));
                }
        }
    }
    __syncthreads();

    // ---- L2: H2 = relu(H1 @ W2 + b2) into registers, K=512 ----
    f32x4 acc2[2][4] = {};
    {
        bf16x8 aq[2][2], bq[3][4];
#pragma unroll
        for (int nt = 0; nt < 4; ++nt) bq[0][nt] = ldsb8(WT2 + (size_t)(wn*64 + nt*16 + l16) * 512 + l4*8);
#pragma unroll
        for (int nt = 0; nt < 4; ++nt) bq[1][nt] = ldsb8(WT2 + (size_t)(wn*64 + nt*16 + l16) * 512 + 32 + l4*8);
#pragma unroll
        for (int mt = 0; mt < 2; ++mt) aq[0][mt] = ldsb8(H + (wm*32 + mt*16 + l16) * 536 + l4*8);
#pragma unroll
        for (int kk = 0; kk < 16; ++kk) {
            if (kk + 2 < 16) {
#pragma unroll
                for (int nt = 0; nt < 4; ++nt)
                    bq[(kk+2)%3][nt] = ldsb8(WT2 + (size_t)(wn*64 + nt*16 + l16) * 512 + (kk+2)*32 + l4*8);
            }
            if (kk + 1 < 16) {
#pragma unroll
                for (int mt = 0; mt < 2; ++mt)
                    aq[(kk+1)&1][mt] = ldsb8(H + (wm*32 + mt*16 + l16) * 536 + (kk+1)*32 + l4*8);
            }
#pragma unroll
            for (int nt = 0; nt < 4; ++nt)
#pragma unroll
                for (int mt = 0; mt < 2; ++mt)
                    acc2[mt][nt] = __builtin_amdgcn_mfma_f32_16x16x32_bf16(aq[kk&1][mt], bq[kk%3][nt], acc2[mt][nt], 0, 0, 0);
        }
    }
    __syncthreads();     // all H1 reads done
    {
#pragma unroll
        for (int nt = 0; nt < 4; ++nt) {
            int col = wn*64 + nt*16 + l16;
            float bias = b2[col];
#pragma unroll
            for (int mt = 0; mt < 2; ++mt)
#pragma unroll
                for (int i = 0; i < 4; ++i) {
                    int row = wm*32 + mt*16 + l4*4 + i;
                    H[row * 536 + col] = f2bf(fmaxf(acc2[mt][nt][i] + bias, 0.f));
                }
        }
    }
    __syncthreads();     // H now holds H2

    // ---- L3: emb = H2 @ W3 + b3, K=512, N=256 ----
    f32x4 acc3[2][2] = {};
    {
        bf16x8 aq[2][2], bq[3][2];
#pragma unroll
        for (int nt = 0; nt < 2; ++nt) bq[0][nt] = ldsb8(WT3 + (size_t)(wn*32 + nt*16 + l16) * 512 + l4*8);
#pragma unroll
        for (int nt = 0; nt < 2; ++nt) bq[1][nt] = ldsb8(WT3 + (size_t)(wn*32 + nt*16 + l16) * 512 + 32 + l4*8);
#pragma unroll
        for (int mt = 0; mt < 2; ++mt) aq[0][mt] = ldsb8(H + (wm*32 + mt*16 + l16) * 536 + l4*8);
#pragma unroll
        for (int kk = 0; kk < 16; ++kk) {
            if (kk + 2 < 16) {
#pragma unroll
                for (int nt = 0; nt < 2; ++nt)
                    bq[(kk+2)%3][nt] = ldsb8(WT3 + (size_t)(wn*32 + nt*16 + l16) * 512 + (kk+2)*32 + l4*8);
            }
            if (kk + 1 < 16) {
#pragma unroll
                for (int mt = 0; mt < 2; ++mt)
                    aq[(kk+1)&1][mt] = ldsb8(H + (wm*32 + mt*16 + l16) * 536 + (kk+1)*32 + l4*8);
            }
#pragma unroll
            for (int nt = 0; nt < 2; ++nt)
#pragma unroll
                for (int mt = 0; mt < 2; ++mt)
                    acc3[mt][nt] = __builtin_amdgcn_mfma_f32_16x16x32_bf16(aq[kk&1][mt], bq[kk%3][nt], acc3[mt][nt], 0, 0, 0);
        }
    }

    // ---- epilogue: emb -> global (RM + CM, bf16) ----
    {
        unsigned short* eR = embOut + (size_t)bt * 32768;
        unsigned short* eC = eR + 16384;
#pragma unroll
        for (int nt = 0; nt < 2; ++nt) {
            int col = wn*32 + nt*16 + l16;
            float bias = b3[col];
#pragma unroll
            for (int mt = 0; mt < 2; ++mt)
#pragma unroll
                for (int i = 0; i < 4; ++i) {
                    int row = wm*32 + mt*16 + l4*4 + i;
                    unsigned short u = f2bf(acc3[mt][nt][i] + bias);
                    eR[row * 256 + col] = u;
                    eC[col * 64 + row]  = u;
                }
        }
    }
}

// ======================= K2: attention =======================
// LDS: W1A [16][72]us @0 (2304) ; TCM [256][40]us @2304 (20480) ;
//      TF [16][260]f32 @22784 (16640) ; W2A [64][40]us @39424 (5120) ;
//      MK [64]i32 @44544 (256) ; SRED f32[128] @44800 (512)  -> 45312
#define K2_LDS 45312

__global__ void attn_kernel(const int* __restrict__ amask,
                            const unsigned short* __restrict__ tqbf,
                            const unsigned short* __restrict__ emb,
                            float* __restrict__ outT, float* __restrict__ outC)
{
    extern __shared__ __align__(16) char smem[];
    unsigned short* W1A = (unsigned short*)smem;
    unsigned short* TCM = (unsigned short*)(smem + 2304);
    float*          TF  = (float*)(smem + 22784);
    unsigned short* W2A = (unsigned short*)(smem + 39424);
    int*            MK  = (int*)(smem + 44544);
    float*          SMX = (float*)(smem + 44800);   // [16][4]
    float*          SSM = SMX + 64;                 // [16][4]

    const int bt = blockIdx.x, tid = threadIdx.x;
    const int lane = tid & 63, w = tid >> 6;
    const int l16 = lane & 15, l4 = lane >> 4;
    const unsigned short* eR = emb + (size_t)bt * 32768;
    const unsigned short* eC = eR + 16384;

    if (tid < 64) MK[tid] = amask[(size_t)bt * 64 + tid];
    __syncthreads();

    // ---- P1: S1 tile [16 q][16 ag], ag-range = w*16.. ----
    float sv[4]; int msk;
    {
        f32x4 acc = {};
#pragma unroll
        for (int kk = 0; kk < 8; ++kk) {
            int ko = kk*32 + l4*8;
            bf16x8 a = ldsb8(tqbf + l16 * 256 + ko);
            bf16x8 b = ldsb8(eR + (w*16 + l16) * 256 + ko);
            acc = __builtin_amdgcn_mfma_f32_16x16x32_bf16(a, b, acc, 0, 0, 0);
        }
        msk = MK[w*16 + l16];
#pragma unroll
        for (int i = 0; i < 4; ++i) sv[i] = msk ? acc[i] * 0.0625f : -3.0e38f;
        float mx[4];
#pragma unroll
        for (int i = 0; i < 4; ++i) {
            float m = sv[i];
#pragma unroll
            for (int off = 1; off < 16; off <<= 1) m = fmaxf(m, __shfl_xor(m, off, 16));
            mx[i] = m;
        }
        if (l16 == 0) {
#pragma unroll
            for (int i = 0; i < 4; ++i) SMX[(l4*4 + i) * 4 + w] = mx[i];
        }
    }
    __syncthreads();
    float ev[4];
    {
#pragma unroll
        for (int i = 0; i < 4; ++i) {
            int q = l4*4 + i;
            float g = fmaxf(fmaxf(SMX[q*4+0], SMX[q*4+1]), fmaxf(SMX[q*4+2], SMX[q*4+3]));
            ev[i] = msk ? __expf(sv[i] - g) : 0.f;
            float s = ev[i];
#pragma unroll
            for (int off = 1; off < 16; off <<= 1) s += __shfl_xor(s, off, 16);
            if (l16 == 0) SSM[q*4 + w] = s;
        }
    }
    __syncthreads();
    {
#pragma unroll
        for (int i = 0; i < 4; ++i) {
            int q = l4*4 + i;
            float tot = SSM[q*4+0] + SSM[q*4+1] + SSM[q*4+2] + SSM[q*4+3];
            float w1 = ev[i] * (1.0f / fmaxf(tot, 1e-8f));
            W1A[q * 72 + w*16 + l16] = f2bf(w1);
        }
    }
    __syncthreads();

    // ---- P2: T^T[d][q] = EMB_CM @ W1A^T ; write TCM (bf16) + TF (f32) ----
    {
        bf16x8 bW[2];
#pragma unroll
        for (int kk = 0; kk < 2; ++kk) bW[kk] = ldsb8(W1A + l16 * 72 + kk*32 + l4*8);
#pragma unroll
        for (int p = 0; p < 4; ++p) {
            int dt = w + p * 4;
            f32x4 acc = {};
#pragma unroll
            for (int kk = 0; kk < 2; ++kk) {
                bf16x8 a = ldsb8(eC + (dt*16 + l16) * 64 + kk*32 + l4*8);
                acc = __builtin_amdgcn_mfma_f32_16x16x32_bf16(a, bW[kk], acc, 0, 0, 0);
            }
#pragma unroll
            for (int i = 0; i < 4; ++i) {
                int d = dt*16 + l4*4 + i;
                TCM[d * 40 + l16]      = f2bf(acc[i]);
                TCM[d * 40 + 16 + l16] = 0;
                TF[l16 * 260 + d]      = acc[i];
            }
        }
    }
    __syncthreads();

    // ---- outT (coalesced from TF) ----
    {
        float* oT = outT + (size_t)bt * 4096;
#pragma unroll
        for (int it = 0; it < 16; ++it) {
            int idx = tid + it * 256;
            oT[idx] = TF[(idx >> 8) * 260 + (idx & 255)];
        }
    }

    // ---- P3: S2[ag][q] = EMB_RM . T^T ; softmax over q; -> W2A ----
    {
        f32x4 acc = {};
#pragma unroll
        for (int kk = 0; kk < 8; ++kk) {
            int ko = kk*32 + l4*8;
            bf16x8 a = ldsb8(eR + (w*16 + l16) * 256 + ko);
            const float* tp = TF + l16 * 260 + ko;
            f32x4 t0 = *(const f32x4*)tp;
            f32x4 t1 = *(const f32x4*)(tp + 4);
            bf16x8 b;
            b[0]=(__bf16)t0.x; b[1]=(__bf16)t0.y; b[2]=(__bf16)t0.z; b[3]=(__bf16)t0.w;
            b[4]=(__bf16)t1.x; b[5]=(__bf16)t1.y; b[6]=(__bf16)t1.z; b[7]=(__bf16)t1.w;
            acc = __builtin_amdgcn_mfma_f32_16x16x32_bf16(a, b, acc, 0, 0, 0);
        }
#pragma unroll
        for (int i = 0; i < 4; ++i) {
            float s = acc[i] * 0.0625f;
            float m = s;
#pragma unroll
            for (int off = 1; off < 16; off <<= 1) m = fmaxf(m, __shfl_xor(m, off, 16));
            float e = __expf(s - m);
            float su = e;
#pragma unroll
            for (int off = 1; off < 16; off <<= 1) su += __shfl_xor(su, off, 16);
            float w2 = e / su;
            int ag = w*16 + l4*4 + i;
            W2A[ag * 40 + l16]      = f2bf(w2);
            W2A[ag * 40 + 16 + l16] = 0;
        }
    }
    __syncthreads();

    // ---- P4: ctx[ag][d] = (W2A @ T) * mask  (overwrites emb region) ----
    {
        float* oC = outC + (size_t)bt * 16384;
        bf16x8 a = ldsb8(W2A + (w*16 + l16) * 40 + l4*8);
#pragma unroll
        for (int dt = 0; dt < 16; ++dt) {
            bf16x8 b = ldsb8(TCM + (dt*16 + l16) * 40 + l4*8);
            f32x4 acc = {};
            acc = __builtin_amdgcn_mfma_f32_16x16x32_bf16(a, b, acc, 0, 0, 0);
#pragma unroll
            for (int i = 0; i < 4; ++i) {
                int ag = w*16 + l4*4 + i;
                float m = (float)MK[ag];
                oC[ag * 256 + dt*16 + l16] = acc[i] * m;
            }
        }
    }
}

extern "C" void kernel_launch(void* const* d_in, const int* in_sizes, int n_in,
                              void* d_out, int out_size, void* d_ws, size_t ws_size,
                              hipStream_t stream) {
    (void)in_sizes; (void)n_in; (void)out_size; (void)ws_size;
    const float* obs   = (const float*)d_in[0];
    const int*   amask = (const int*)d_in[1];
    const float* W1    = (const float*)d_in[2];
    const float* b1    = (const float*)d_in[3];
    const float* W2    = (const float*)d_in[4];
    const float* b2    = (const float*)d_in[5];
    const float* W3    = (const float*)d_in[6];
    const float* b3    = (const float*)d_in[7];
    const float* tq    = (const float*)d_in[8];

    unsigned short* wt1  = (unsigned short*)d_ws;      // [512][128]
    unsigned short* wt2  = wt1 + 512 * 128;            // [512][512]
    unsigned short* wt3  = wt2 + 512 * 512;            // [256][512]
    unsigned short* tqbf = wt3 + 256 * 512;            // [16][256]

    float* outT = (float*)d_out;
    float* outC = outT + (size_t)BT_TOTAL * 16 * 256;
    unsigned short* embWS = (unsigned short*)outC;     // emb staged in outC region

    transpose_all<<<449, 256, 0, stream>>>(W1, W2, W3, tq, wt1, wt2, wt3, tqbf);
    mlp_kernel<<<BT_TOTAL, 1024, K1_LDS, stream>>>(
        obs, wt1, b1, wt2, b2, wt3, b3, embWS);
    attn_kernel<<<BT_TOTAL, 256, K2_LDS, stream>>>(
        amask, tqbf, embWS, outT, outC);
}

// Round 6
// 142.155 us; speedup vs baseline: 1.8628x; 1.8517x over previous
//
#include <hip/hip_runtime.h>
#include <hip/hip_bf16.h>

#define BT_TOTAL 1024

typedef __bf16 bf16x8 __attribute__((ext_vector_type(8)));
typedef float  f32x4  __attribute__((ext_vector_type(4)));
typedef int    i32x4  __attribute__((ext_vector_type(4)));
typedef short  s16x4  __attribute__((ext_vector_type(4)));

__device__ inline unsigned short f2bf(float f) {
    unsigned int u = __builtin_bit_cast(unsigned int, f);
    u = (u + 0x7FFFu + ((u >> 16) & 1u)) >> 16;
    return (unsigned short)u;
}

__device__ inline bf16x8 ldsb8(const unsigned short* p) {
    i32x4 t = *(const i32x4*)p;
    return __builtin_bit_cast(bf16x8, t);
}

__device__ __forceinline__ void gl_lds16(const void* g, void* l) {
    __builtin_amdgcn_global_load_lds(
        (const __attribute__((address_space(1))) void*)g,
        (__attribute__((address_space(3))) void*)l, 16, 0, 0);
}

// swizzled byte offset of element (n, kl) inside a [N][32] bf16 chunk
__device__ __forceinline__ int swz_off(int n, int kl) {
    return ((n >> 1) << 7) + ((((n & 1) << 6) | (kl << 1)) ^ (((n >> 1) & 7) << 4));
}

template<int CALLS>
__device__ __forceinline__ void stage_tile(const void* chunk, char* dst, int wv, int lane) {
#pragma unroll
    for (int c = 0; c < CALLS; ++c) {
        int off = wv * (CALLS * 1024) + c * 1024;
        gl_lds16((const char*)chunk + off + lane * 16, dst + off);
    }
}

// ---------------- prep: weights -> swizzled bf16 chunks ----------------
// L1: 4 chunks [512][32] ; L2: 16 chunks [512][32] ; L3: 16 chunks [256][32]
__global__ __launch_bounds__(512) void prep_weights(
    const float* __restrict__ W1, const float* __restrict__ W2,
    const float* __restrict__ W3,
    unsigned short* __restrict__ wt1, unsigned short* __restrict__ wt2,
    unsigned short* __restrict__ wt3)
{
    int b = blockIdx.x, tid = threadIdx.x;
    if (b < 4) {                    // L1: K=128, N=512
        int k0 = b * 32;
        unsigned short* d = wt1 + b * 16384;
        for (int kl = 0; kl < 32; ++kl) {
            int n = tid;
            float v = W1[(size_t)(k0 + kl) * 512 + n];
            d[swz_off(n, kl) >> 1] = f2bf(v);
        }
    } else if (b < 20) {            // L2: K=512, N=512
        int c = b - 4, k0 = c * 32;
        unsigned short* d = wt2 + c * 16384;
        for (int kl = 0; kl < 32; ++kl) {
            int n = tid;
            float v = W2[(size_t)(k0 + kl) * 512 + n];
            d[swz_off(n, kl) >> 1] = f2bf(v);
        }
    } else {                        // L3: K=512, N=256  (16 chunks!)
        int c = b - 20, k0 = c * 32;
        unsigned short* d = wt3 + c * 8192;
        for (int i = 0; i < 16; ++i) {
            int e = i * 512 + tid;
            int kl = e >> 8, n = e & 255;
            float v = W3[(size_t)(k0 + kl) * 256 + n];
            d[swz_off(n, kl) >> 1] = f2bf(v);
        }
    }
}

// ======================= K1: fused MLP, 2-phase gload_lds pipeline =======================
// LDS: OBS [64][136]us @0 (17408) ; H [64][520]us @17408 (66560) ;
//      B0 @83968 (32768) ; B1 @116736 (32768)  -> 149504
#define K1_LDS 149504

__global__ __launch_bounds__(512, 2) void mlp_kernel(
    const float* __restrict__ obs,
    const unsigned short* __restrict__ C1, const float* __restrict__ b1,
    const unsigned short* __restrict__ C2, const float* __restrict__ b2,
    const unsigned short* __restrict__ C3, const float* __restrict__ b3,
    unsigned short* __restrict__ embOut)   // per bt: RM [64][256] then CM [256][64]
{
    extern __shared__ __align__(16) char smem[];
    unsigned short* OBS = (unsigned short*)smem;            // [64][136]
    unsigned short* H   = (unsigned short*)(smem + 17408);  // [64][520]
    char* B0 = smem + 83968;
    char* B1 = smem + 116736;
    unsigned short* EMB = (unsigned short*)smem;            // [64][264] (post)

    const int bt = blockIdx.x, tid = threadIdx.x;
    const int lane = tid & 63, wv = tid >> 6;   // 8 waves
    const int l16 = lane & 15, l4 = lane >> 4;

    int boff[4], boff3[2];
#pragma unroll
    for (int nt = 0; nt < 4; ++nt) {
        int n = wv * 64 + nt * 16 + l16;
        boff[nt] = ((n >> 1) << 7) + ((((n & 1) << 6) | (l4 << 4)) ^ (((n >> 1) & 7) << 4));
    }
#pragma unroll
    for (int nt = 0; nt < 2; ++nt) {
        int n = wv * 32 + nt * 16 + l16;
        boff3[nt] = ((n >> 1) << 7) + ((((n & 1) << 6) | (l4 << 4)) ^ (((n >> 1) & 7) << 4));
    }

    // ---- prologue: stage L1 tile 0; convert obs -> bf16 LDS ----
    stage_tile<4>(C1, B0, wv, lane);
    {
        const f32x4* src = (const f32x4*)(obs + (size_t)bt * 8192);
#pragma unroll
        for (int i = 0; i < 4; ++i) {
            int idx = tid + i * 512;
            f32x4 v = src[idx];
            int row = idx >> 5, c4 = idx & 31;
            s16x4 s;
            s[0] = (short)f2bf(v.x); s[1] = (short)f2bf(v.y);
            s[2] = (short)f2bf(v.z); s[3] = (short)f2bf(v.w);
            *(s16x4*)(OBS + row * 136 + c4 * 4) = s;
        }
    }
    __syncthreads();

    // ---- L1: 4 steps ----
    f32x4 acc1[4][4] = {};
    for (int t = 0; t < 4; ++t) {
        if (t < 3) stage_tile<4>(C1 + (size_t)(t + 1) * 16384, (t & 1) ? B0 : B1, wv, lane);
        else       stage_tile<4>(C2, B0, wv, lane);
        const char* bb = (t & 1) ? B1 : B0;
        bf16x8 afr[4], bfr[4];
#pragma unroll
        for (int mt = 0; mt < 4; ++mt)
            afr[mt] = ldsb8(OBS + (mt * 16 + l16) * 136 + t * 32 + l4 * 8);
#pragma unroll
        for (int nt = 0; nt < 4; ++nt)
            bfr[nt] = ldsb8((const unsigned short*)(bb + boff[nt]));
#pragma unroll
        for (int nt = 0; nt < 4; ++nt)
#pragma unroll
            for (int mt = 0; mt < 4; ++mt)
                acc1[mt][nt] = __builtin_amdgcn_mfma_f32_16x16x32_bf16(afr[mt], bfr[nt], acc1[mt][nt], 0, 0, 0);
        __syncthreads();
    }
    {
#pragma unroll
        for (int nt = 0; nt < 4; ++nt) {
            int col = wv * 64 + nt * 16 + l16;
            float bias = b1[col];
#pragma unroll
            for (int mt = 0; mt < 4; ++mt)
#pragma unroll
                for (int i = 0; i < 4; ++i) {
                    int row = mt * 16 + l4 * 4 + i;
                    H[row * 520 + col] = f2bf(fmaxf(acc1[mt][nt][i] + bias, 0.f));
                }
        }
    }
    __syncthreads();

    // ---- L2: 16 steps ----
    f32x4 acc2[4][4] = {};
    for (int t = 0; t < 16; ++t) {
        if (t < 15) stage_tile<4>(C2 + (size_t)(t + 1) * 16384, (t & 1) ? B0 : B1, wv, lane);
        else        stage_tile<2>(C3, B0, wv, lane);
        const char* bb = (t & 1) ? B1 : B0;
        bf16x8 afr[4], bfr[4];
#pragma unroll
        for (int mt = 0; mt < 4; ++mt)
            afr[mt] = ldsb8(H + (mt * 16 + l16) * 520 + t * 32 + l4 * 8);
#pragma unroll
        for (int nt = 0; nt < 4; ++nt)
            bfr[nt] = ldsb8((const unsigned short*)(bb + boff[nt]));
#pragma unroll
        for (int nt = 0; nt < 4; ++nt)
#pragma unroll
            for (int mt = 0; mt < 4; ++mt)
                acc2[mt][nt] = __builtin_amdgcn_mfma_f32_16x16x32_bf16(afr[mt], bfr[nt], acc2[mt][nt], 0, 0, 0);
        __syncthreads();
    }
    {
#pragma unroll
        for (int nt = 0; nt < 4; ++nt) {
            int col = wv * 64 + nt * 16 + l16;
            float bias = b2[col];
#pragma unroll
            for (int mt = 0; mt < 4; ++mt)
#pragma unroll
                for (int i = 0; i < 4; ++i) {
                    int row = mt * 16 + l4 * 4 + i;
                    H[row * 520 + col] = f2bf(fmaxf(acc2[mt][nt][i] + bias, 0.f));
                }
        }
    }
    __syncthreads();

    // ---- L3: 16 steps (K=512!), N=256 ----
    f32x4 acc3[4][2] = {};
    for (int t = 0; t < 16; ++t) {
        if (t < 15) stage_tile<2>(C3 + (size_t)(t + 1) * 8192, (t & 1) ? B0 : B1, wv, lane);
        const char* bb = (t & 1) ? B1 : B0;
        bf16x8 afr[4], bfr[2];
#pragma unroll
        for (int mt = 0; mt < 4; ++mt)
            afr[mt] = ldsb8(H + (mt * 16 + l16) * 520 + t * 32 + l4 * 8);
#pragma unroll
        for (int nt = 0; nt < 2; ++nt)
            bfr[nt] = ldsb8((const unsigned short*)(bb + boff3[nt]));
#pragma unroll
        for (int nt = 0; nt < 2; ++nt)
#pragma unroll
            for (int mt = 0; mt < 4; ++mt)
                acc3[mt][nt] = __builtin_amdgcn_mfma_f32_16x16x32_bf16(afr[mt], bfr[nt], acc3[mt][nt], 0, 0, 0);
        __syncthreads();
    }

    // ---- emb epilogue: bf16 tile in LDS, then coalesced RM + CM global writes ----
    {
#pragma unroll
        for (int nt = 0; nt < 2; ++nt) {
            int col = wv * 32 + nt * 16 + l16;
            float bias = b3[col];
#pragma unroll
            for (int mt = 0; mt < 4; ++mt)
#pragma unroll
                for (int i = 0; i < 4; ++i) {
                    int row = mt * 16 + l4 * 4 + i;
                    EMB[row * 264 + col] = f2bf(acc3[mt][nt][i] + bias);
                }
        }
    }
    __syncthreads();
    {
        unsigned short* eR = embOut + (size_t)bt * 32768;
        unsigned short* eC = eR + 16384;
        // RM: [64][256] = 2048 x 16B groups
#pragma unroll
        for (int u = 0; u < 4; ++u) {
            int uu = tid + u * 512;                 // 0..2047
            int row = uu >> 5, c8 = (uu & 31) * 8;
            i32x4 v = *(const i32x4*)(EMB + row * 264 + c8);
            *(i32x4*)(eR + uu * 8) = v;             // eR[row*256 + c8]
        }
        // CM: [256][64] = 2048 x 16B groups
#pragma unroll
        for (int u = 0; u < 4; ++u) {
            int v = tid + u * 512;                  // 0..2047
            int col = v >> 3, r8 = (v & 7) * 8;
            i32x4 w;
#pragma unroll
            for (int j = 0; j < 4; ++j) {
                unsigned int a = EMB[(r8 + 2 * j) * 264 + col];
                unsigned int b = EMB[(r8 + 2 * j + 1) * 264 + col];
                w[j] = (int)(a | (b << 16));
            }
            *(i32x4*)(eC + v * 8) = w;              // eC[col*64 + r8]
        }
    }
}

// ======================= K2: attention =======================
// LDS: W1A [16][72]us @0 (2304) ; TCM [256][40]us @2304 (20480) ;
//      TF [16][260]f32 @22784 (16640) ; W2A [64][40]us @39424 (5120) ;
//      MK [64]i32 @44544 (256) ; SMX/SSM @44800 (512) ; TQ [16][264]us @45312 (8448)
#define K2_LDS 53760

__global__ void attn_kernel(const int* __restrict__ amask,
                            const float* __restrict__ tq,
                            const unsigned short* __restrict__ emb,
                            float* __restrict__ outT, float* __restrict__ outC)
{
    extern __shared__ __align__(16) char smem[];
    unsigned short* W1A = (unsigned short*)smem;
    unsigned short* TCM = (unsigned short*)(smem + 2304);
    float*          TF  = (float*)(smem + 22784);
    unsigned short* W2A = (unsigned short*)(smem + 39424);
    int*            MK  = (int*)(smem + 44544);
    float*          SMX = (float*)(smem + 44800);
    float*          SSM = SMX + 64;
    unsigned short* TQ  = (unsigned short*)(smem + 45312);  // [16][264]

    const int bt = blockIdx.x, tid = threadIdx.x;
    const int lane = tid & 63, w = tid >> 6;
    const int l16 = lane & 15, l4 = lane >> 4;
    const unsigned short* eR = emb + (size_t)bt * 32768;
    const unsigned short* eC = eR + 16384;

    if (tid < 64) MK[tid] = amask[(size_t)bt * 64 + tid];
#pragma unroll
    for (int i = 0; i < 16; ++i) {
        int idx = tid + i * 256;                // 0..4095
        int row = idx >> 8, col = idx & 255;
        TQ[row * 264 + col] = f2bf(tq[idx]);
    }
    __syncthreads();

    float sv[4]; int msk;
    {
        f32x4 acc = {};
#pragma unroll
        for (int kk = 0; kk < 8; ++kk) {
            int ko = kk*32 + l4*8;
            bf16x8 a = ldsb8(TQ + l16 * 264 + ko);
            bf16x8 b = ldsb8(eR + (w*16 + l16) * 256 + ko);
            acc = __builtin_amdgcn_mfma_f32_16x16x32_bf16(a, b, acc, 0, 0, 0);
        }
        msk = MK[w*16 + l16];
#pragma unroll
        for (int i = 0; i < 4; ++i) sv[i] = msk ? acc[i] * 0.0625f : -3.0e38f;
        float mx[4];
#pragma unroll
        for (int i = 0; i < 4; ++i) {
            float m = sv[i];
#pragma unroll
            for (int off = 1; off < 16; off <<= 1) m = fmaxf(m, __shfl_xor(m, off, 16));
            mx[i] = m;
        }
        if (l16 == 0) {
#pragma unroll
            for (int i = 0; i < 4; ++i) SMX[(l4*4 + i) * 4 + w] = mx[i];
        }
    }
    __syncthreads();
    float ev[4];
    {
#pragma unroll
        for (int i = 0; i < 4; ++i) {
            int q = l4*4 + i;
            float g = fmaxf(fmaxf(SMX[q*4+0], SMX[q*4+1]), fmaxf(SMX[q*4+2], SMX[q*4+3]));
            ev[i] = msk ? __expf(sv[i] - g) : 0.f;
            float s = ev[i];
#pragma unroll
            for (int off = 1; off < 16; off <<= 1) s += __shfl_xor(s, off, 16);
            if (l16 == 0) SSM[q*4 + w] = s;
        }
    }
    __syncthreads();
    {
#pragma unroll
        for (int i = 0; i < 4; ++i) {
            int q = l4*4 + i;
            float tot = SSM[q*4+0] + SSM[q*4+1] + SSM[q*4+2] + SSM[q*4+3];
            float w1 = ev[i] * (1.0f / fmaxf(tot, 1e-8f));
            W1A[q * 72 + w*16 + l16] = f2bf(w1);
        }
    }
    __syncthreads();

    {
        bf16x8 bW[2];
#pragma unroll
        for (int kk = 0; kk < 2; ++kk) bW[kk] = ldsb8(W1A + l16 * 72 + kk*32 + l4*8);
#pragma unroll
        for (int p = 0; p < 4; ++p) {
            int dt = w + p * 4;
            f32x4 acc = {};
#pragma unroll
            for (int kk = 0; kk < 2; ++kk) {
                bf16x8 a = ldsb8(eC + (dt*16 + l16) * 64 + kk*32 + l4*8);
                acc = __builtin_amdgcn_mfma_f32_16x16x32_bf16(a, bW[kk], acc, 0, 0, 0);
            }
#pragma unroll
            for (int i = 0; i < 4; ++i) {
                int d = dt*16 + l4*4 + i;
                TCM[d * 40 + l16]      = f2bf(acc[i]);
                TCM[d * 40 + 16 + l16] = 0;
                TF[l16 * 260 + d]      = acc[i];
            }
        }
    }
    __syncthreads();

    {
        float* oT = outT + (size_t)bt * 4096;
#pragma unroll
        for (int it = 0; it < 16; ++it) {
            int idx = tid + it * 256;
            oT[idx] = TF[(idx >> 8) * 260 + (idx & 255)];
        }
    }

    {
        f32x4 acc = {};
#pragma unroll
        for (int kk = 0; kk < 8; ++kk) {
            int ko = kk*32 + l4*8;
            bf16x8 a = ldsb8(eR + (w*16 + l16) * 256 + ko);
            const float* tp = TF + l16 * 260 + ko;
            f32x4 t0 = *(const f32x4*)tp;
            f32x4 t1 = *(const f32x4*)(tp + 4);
            bf16x8 b;
            b[0]=(__bf16)t0.x; b[1]=(__bf16)t0.y; b[2]=(__bf16)t0.z; b[3]=(__bf16)t0.w;
            b[4]=(__bf16)t1.x; b[5]=(__bf16)t1.y; b[6]=(__bf16)t1.z; b[7]=(__bf16)t1.w;
            acc = __builtin_amdgcn_mfma_f32_16x16x32_bf16(a, b, acc, 0, 0, 0);
        }
#pragma unroll
        for (int i = 0; i < 4; ++i) {
            float s = acc[i] * 0.0625f;
            float m = s;
#pragma unroll
            for (int off = 1; off < 16; off <<= 1) m = fmaxf(m, __shfl_xor(m, off, 16));
            float e = __expf(s - m);
            float su = e;
#pragma unroll
            for (int off = 1; off < 16; off <<= 1) su += __shfl_xor(su, off, 16);
            float w2 = e / su;
            int ag = w*16 + l4*4 + i;
            W2A[ag * 40 + l16]      = f2bf(w2);
            W2A[ag * 40 + 16 + l16] = 0;
        }
    }
    __syncthreads();

    {
        float* oC = outC + (size_t)bt * 16384;
        bf16x8 a = ldsb8(W2A + (w*16 + l16) * 40 + l4*8);
#pragma unroll
        for (int dt = 0; dt < 16; ++dt) {
            bf16x8 b = ldsb8(TCM + (dt*16 + l16) * 40 + l4*8);
            f32x4 acc = {};
            acc = __builtin_amdgcn_mfma_f32_16x16x32_bf16(a, b, acc, 0, 0, 0);
#pragma unroll
            for (int i = 0; i < 4; ++i) {
                int ag = w*16 + l4*4 + i;
                float m = (float)MK[ag];
                oC[ag * 256 + dt*16 + l16] = acc[i] * m;
            }
        }
    }
}

extern "C" void kernel_launch(void* const* d_in, const int* in_sizes, int n_in,
                              void* d_out, int out_size, void* d_ws, size_t ws_size,
                              hipStream_t stream) {
    (void)in_sizes; (void)n_in; (void)out_size; (void)ws_size;
    const float* obs   = (const float*)d_in[0];
    const int*   amask = (const int*)d_in[1];
    const float* W1    = (const float*)d_in[2];
    const float* b1    = (const float*)d_in[3];
    const float* W2    = (const float*)d_in[4];
    const float* b2    = (const float*)d_in[5];
    const float* W3    = (const float*)d_in[6];
    const float* b3    = (const float*)d_in[7];
    const float* tq    = (const float*)d_in[8];

    unsigned short* wt1 = (unsigned short*)d_ws;       // 4  chunks x 16384 us
    unsigned short* wt2 = wt1 + 65536;                 // 16 chunks x 16384 us
    unsigned short* wt3 = wt2 + 262144;                // 16 chunks x 8192 us

    float* outT = (float*)d_out;
    float* outC = outT + (size_t)BT_TOTAL * 16 * 256;
    unsigned short* embWS = (unsigned short*)outC;     // emb staged in outC region

    prep_weights<<<36, 512, 0, stream>>>(W1, W2, W3, wt1, wt2, wt3);
    mlp_kernel<<<BT_TOTAL, 512, K1_LDS, stream>>>(
        obs, wt1, b1, wt2, b2, wt3, b3, embWS);
    attn_kernel<<<BT_TOTAL, 256, K2_LDS, stream>>>(
        amask, tq, embWS, outT, outC);
}